// Round 5
// baseline (116.846 us; speedup 1.0000x reference)
//
#include <hip/hip_runtime.h>

#define N_FEAT 1024
#define N_LAYER 4
#define RPG 8              // rows per LDS group/tile (32 KB)
#define GPB 4              // groups per block
#define AS1 __attribute__((address_space(1)))
#define AS3 __attribute__((address_space(3)))

// Algebra: xi = A_i*x0 + C_i, C_i = sum_{j<i} b_j (row-independent).
//   p_i = <x0,w_i>, e_i = <C_i,w_i>; A_{i+1} = A_i*(1+p_i) + e_i;
//   out = A_4*x0 + csum.
//
// Barrier-free async pipeline: wave w stages LDS rows 2w..2w+1 and consumes
// ONLY those rows -> cross-wave sync is never needed. R4's __syncthreads
// (which drains vmcnt to 0 every group: ~3K-cycle transfer tail + ~900-cycle
// HBM latency tail per group, the m97-structure stall) is replaced with
// wave-local counted s_waitcnt vmcnt(N). Per-iteration issue order:
//   L(t+1): 8x global_load_lds | wait L(t) | 8x ds_read_b128 + dot |
//   butterfly | S(t): 8x global_store_dwordx4
// Newer-than-L(t) at the wait = S(t-1)(8) + L(t+1)(8) = 16 -> vmcnt(16)
// steady state; vmcnt(8) at t=0 (no stores yet) and t=GPB-1 (no prefetch).
// vmcnt retires in order (m135), so extra compiler-issued ops between the
// asm barriers can only make the wait stricter. Buffer-reuse is wave-local,
// carried by the ds_read->store data dep; asm "memory" + sched_barrier(0)
// pin LDS-aliasing order. Queue never drains: ~16KB/wave in flight.
__global__ __launch_bounds__(256) void crossnet_kernel(
    const float* __restrict__ x,
    const float* __restrict__ weight_w,
    const float* __restrict__ weight_b,
    float* __restrict__ out,
    int n_rows) {
  const int wave = threadIdx.x >> 6;   // 0..3
  const int lane = threadIdx.x & 63;

  __shared__ float buf[2][RPG * N_FEAT];   // 2 x 32 KB

  // ---- hoisted once per kernel: w frags, e, csum (all row-independent) ----
  float4 w[4][N_LAYER];
  float4 csum[4];
  float e[N_LAYER] = {0.f, 0.f, 0.f, 0.f};
#pragma unroll
  for (int c = 0; c < 4; ++c) {
#pragma unroll
    for (int i = 0; i < N_LAYER; ++i)
      w[c][i] = ((const float4*)(weight_w + i * N_FEAT))[c * 64 + lane];
    float4 cum = make_float4(0.f, 0.f, 0.f, 0.f);
#pragma unroll
    for (int i = 0; i < N_LAYER; ++i) {
      if (i > 0)
        e[i] += cum.x * w[c][i].x + cum.y * w[c][i].y +
                cum.z * w[c][i].z + cum.w * w[c][i].w;
      const float4 b = ((const float4*)(weight_b + i * N_FEAT))[c * 64 + lane];
      cum.x += b.x; cum.y += b.y; cum.z += b.z; cum.w += b.w;
    }
    csum[c] = cum;
  }
#pragma unroll
  for (int off = 32; off > 0; off >>= 1)
#pragma unroll
    for (int i = 1; i < N_LAYER; ++i) e[i] += __shfl_xor(e[i], off, 64);

  const int row0 = blockIdx.x * (RPG * GPB);
  if (row0 >= n_rows) return;

  // Wave w stages its own rows 2w,2w+1 of the group (8 x 16B/lane = 8 KB).
  auto stage = [&](int bsel, int grow) {
#pragma unroll
    for (int j = 0; j < 8; ++j) {
      const float* gsrc = x + (size_t)(grow + 2 * wave + (j >> 2)) * N_FEAT +
                          ((j & 3) * 64 + lane) * 4;
      float* ldst = &buf[bsel][(wave * 2 + (j >> 2)) * N_FEAT + (j & 3) * 256];
      __builtin_amdgcn_global_load_lds((const AS1 unsigned int*)gsrc,
                                       (AS3 unsigned int*)ldst, 16, 0, 0);
    }
  };

  stage(0, row0);

#pragma unroll
  for (int t = 0; t < GPB; ++t) {
    const int grow = row0 + t * RPG;

    __builtin_amdgcn_sched_barrier(0);
    if (t + 1 < GPB) stage((t + 1) & 1, grow + RPG);

    // Wait for this group's own staging (wave-local; no block barrier).
    if (t == 0 || t == GPB - 1) {
      asm volatile("s_waitcnt vmcnt(8)" ::: "memory");
    } else {
      asm volatile("s_waitcnt vmcnt(16)" ::: "memory");
    }
    __builtin_amdgcn_sched_barrier(0);

    const float* B = buf[t & 1];

    // ---- dot phase: read own 2 rows from LDS, hold xv in regs ----
    float4 xv[2][4];
    float p[2 * N_LAYER];
#pragma unroll
    for (int k = 0; k < 2 * N_LAYER; ++k) p[k] = 0.f;
#pragma unroll
    for (int r = 0; r < 2; ++r) {
#pragma unroll
      for (int c = 0; c < 4; ++c) {
        xv[r][c] = *(const float4*)&B[(wave * 2 + r) * N_FEAT +
                                      (c * 64 + lane) * 4];
#pragma unroll
        for (int i = 0; i < N_LAYER; ++i) {
          p[r * N_LAYER + i] += xv[r][c].x * w[c][i].x + xv[r][c].y * w[c][i].y +
                                xv[r][c].z * w[c][i].z + xv[r][c].w * w[c][i].w;
        }
      }
    }

    // ---- butterfly: 8 p-values, 6 steps ----
#pragma unroll
    for (int off = 32; off > 0; off >>= 1)
#pragma unroll
      for (int k = 0; k < 2 * N_LAYER; ++k) p[k] += __shfl_xor(p[k], off, 64);

    // ---- recurrence + store (xv in regs: x read from HBM exactly once) ----
#pragma unroll
    for (int r = 0; r < 2; ++r) {
      float A = 1.f;
#pragma unroll
      for (int i = 0; i < N_LAYER; ++i)
        A += A * p[r * N_LAYER + i] + e[i];
      const size_t row = grow + wave * 2 + r;
#pragma unroll
      for (int c = 0; c < 4; ++c) {
        float4 o;
        o.x = fmaf(xv[r][c].x, A, csum[c].x);
        o.y = fmaf(xv[r][c].y, A, csum[c].y);
        o.z = fmaf(xv[r][c].z, A, csum[c].z);
        o.w = fmaf(xv[r][c].w, A, csum[c].w);
        ((float4*)out)[row * 256 + c * 64 + lane] = o;
      }
    }
  }
}

extern "C" void kernel_launch(void* const* d_in, const int* in_sizes, int n_in,
                              void* d_out, int out_size, void* d_ws, size_t ws_size,
                              hipStream_t stream) {
  const float* x = (const float*)d_in[0];
  const float* ww = (const float*)d_in[1];
  const float* wb = (const float*)d_in[2];
  float* out = (float*)d_out;

  const int n_rows = in_sizes[0] / N_FEAT;            // 16384
  const int rows_per_block = RPG * GPB;               // 32
  const int n_blocks = (n_rows + rows_per_block - 1) / rows_per_block;  // 512
  crossnet_kernel<<<n_blocks, 256, 0, stream>>>(x, ww, wb, out, n_rows);
}